// Round 17
// baseline (207.922 us; speedup 1.0000x reference)
//
#include <hip/hip_runtime.h>
#include <stdint.h>

#define Q_IN 33152
#define NTILES 1160   // 8 chunks x 145 tiles (1 linear + 144 quad)
#define TPC 145

typedef _Float16 half8 __attribute__((ext_vector_type(8)));
typedef float floatx4 __attribute__((ext_vector_type(4)));
typedef uint32_t uint4v __attribute__((ext_vector_type(4)));

// ---------------------------------------------------------------------------
// Tile table in EXECUTION order, chunk-major: T = kch*145 + tt.
// tt=0: linear segment (i0=-1, jb=32*kch). tt>=1: quad tile Q = kch*144+tt-1,
// group-major (g, jt) with jb = 32*(g+jt), inner s=0..31, i0 = 32g+s.
__global__ void build_tab(uint32_t* tab) {
  int T = blockIdx.x * 256 + threadIdx.x;
  if (T >= NTILES) return;
  int kch = T / TPC, tt = T % TPC;
  int i0, jb;
  if (tt == 0) { i0 = -1; jb = 32 * kch; }
  else {
    int Q = kch * 144 + (tt - 1);
    int grp = Q >> 5, s = Q & 31;
    int g = 0, base = 0;
    for (; g < 8; ++g) { int cnt = 8 - g; if (grp < base + cnt) break; base += cnt; }
    int jt = grp - base;
    i0 = 32 * g + s;
    jb = 32 * (g + jt);
  }
  tab[T] = (((uint32_t)(uint16_t)(short)i0) << 16) | (uint32_t)(uint16_t)jb;
}

// ---------------------------------------------------------------------------
// Main-layer W convert (Oreal=256, NTT=16), transpose-through-LDS (R16-proven).
__global__ void convert_w2(const float* __restrict__ W, _Float16* __restrict__ Wt,
                           const uint32_t* __restrict__ tab) {
  __shared__ float p[256][33];           // pad 33: bank stride 1, conflict-free
  const int T = blockIdx.x;
  const int tid = threadIdx.x;
  uint32_t e = tab[T];
  int i0 = (short)(e >> 16);
  int jb = (int)(e & 0xFFFFu);
  int q0;
  if (i0 < 0) q0 = jb;
  else {
    int qb = 256 + i0 * 256 - (i0 * (i0 - 1)) / 2 - i0;  // q = qb + j
    q0 = qb + jb;
  }
  {
    int c = tid & 31, r0 = tid >> 5;     // r0 in 0..7
#pragma unroll
    for (int it = 0; it < 32; ++it) {
      int row = it * 8 + r0;
      p[row][c] = W[(size_t)row * Q_IN + q0 + c];
    }
  }
  __syncthreads();
#pragma unroll
  for (int rep = 0; rep < 4; ++rep) {
    int idx = rep * 256 + tid;
    int nt = idx >> 6;
    int l = idx & 63;
    int o = nt * 16 + (l & 15);
    int koff = (l >> 4) * 8;
    half8 v;
#pragma unroll
    for (int t = 0; t < 8; ++t) {
      int j = jb + koff + t;
      float f = p[o][koff + t];
      v[t] = (i0 >= 0 && j < i0) ? (_Float16)0.f : (_Float16)f;
    }
    *(half8*)(Wt + (size_t)(T * 16 + nt) * 512 + l * 8) = v;
  }
}

// ---------------------------------------------------------------------------
// Small W convert (layer 2, NTT=1, Oreal=10): proven original path.
__global__ void convert_w(const float* __restrict__ W, _Float16* __restrict__ Wt,
                          const uint32_t* __restrict__ tab, int NTT, int Oreal) {
  int tid = blockIdx.x * 256 + threadIdx.x;
  if (tid >= NTILES * NTT * 64) return;
  int l = tid & 63;
  int nt = (tid >> 6) % NTT;
  int T = tid / (64 * NTT);
  int o = nt * 16 + (l & 15);
  int koff = (l >> 4) * 8;
  half8 v;
#pragma unroll
  for (int t = 0; t < 8; ++t) v[t] = (_Float16)0.f;
  if (o < Oreal) {
    uint32_t e = tab[T];
    int i0 = (short)(e >> 16);
    int jb = (int)(e & 0xFFFFu);
    const float* row = W + (size_t)o * Q_IN;
    if (i0 < 0) {
#pragma unroll
      for (int t = 0; t < 8; ++t) v[t] = (_Float16)row[jb + koff + t];
    } else {
      int qb = 256 + i0 * 256 - (i0 * (i0 - 1)) / 2 - i0;  // q = qb + j
#pragma unroll
      for (int t = 0; t < 8; ++t) {
        int j = jb + koff + t;
        if (j >= i0) v[t] = (_Float16)row[qb + j];
      }
    }
  }
  *(half8*)(Wt + (size_t)(T * NTT + nt) * 512 + l * 8) = v;
}

// ---------------------------------------------------------------------------
// reduce partials + bias -> h in f16, ALREADY in the hT byte layout.
__global__ void reduce_h16(const float* __restrict__ part, const float* __restrict__ bias,
                           char* __restrict__ h) {
  int t = blockIdx.x * 256 + threadIdx.x;     // 262144 threads
  int row = t >> 6, c4 = (t & 63) << 2;
  float4 acc = *(const float4*)(bias + c4);
#pragma unroll
  for (int k = 0; k < 8; ++k) {
    float4 p = *(const float4*)(part + (size_t)k * 1048576 + t * 4);
    acc.x += p.x; acc.y += p.y; acc.z += p.z; acc.w += p.w;
  }
  _Float16 hv[4] = {(_Float16)acc.x, (_Float16)acc.y, (_Float16)acc.z, (_Float16)acc.w};
  *(uint64_t*)(h + (size_t)row * 512 + ((c4 * 2) ^ ((row & 7) << 4))) =
      *(const uint64_t*)hv;
}

// reduce partials + bias -> out (4096 x 10), part2 stride 16, 16 partials
__global__ void reduce_out(const float* __restrict__ part2, const float* __restrict__ b2,
                           float* __restrict__ out) {
  int t = blockIdx.x * 256 + threadIdx.x;     // 40960
  if (t >= 40960) return;
  int b = t / 10, o = t - b * 10;
  float acc = b2[o];
#pragma unroll
  for (int k = 0; k < 16; ++k) acc += part2[(size_t)k * 65536 + b * 16 + o];
  out[t] = acc;
}

__device__ inline floatx4 mfma16(half8 a, half8 b, floatx4 c) {
  return __builtin_amdgcn_mfma_f32_16x16x32_f16(a, b, c, 0, 0, 0);
}

__device__ inline void gload_lds16(const void* g, void* l) {
  __builtin_amdgcn_global_load_lds(
      (const __attribute__((address_space(1))) uint32_t*)g,
      (__attribute__((address_space(3))) uint32_t*)l, 16, 0, 0);
}

// a * broadcast(lo/hi half of s) via v_pk_mul_f16 op_sel (R9-proven)
__device__ inline half8 splat_mul_lo(half8 a, uint32_t s) {
  uint4v av = __builtin_bit_cast(uint4v, a), r;
#pragma unroll
  for (int k = 0; k < 4; ++k)
    asm("v_pk_mul_f16 %0, %1, %2 op_sel:[0,0] op_sel_hi:[1,0]"
        : "=v"(r[k]) : "v"(av[k]), "v"(s));
  return __builtin_bit_cast(half8, r);
}
__device__ inline half8 splat_mul_hi(half8 a, uint32_t s) {
  uint4v av = __builtin_bit_cast(uint4v, a), r;
#pragma unroll
  for (int k = 0; k < 4; ++k)
    asm("v_pk_mul_f16 %0, %1, %2 op_sel:[0,1] op_sel_hi:[1,1]"
        : "=v"(r[k]) : "v"(av[k]), "v"(s));
  return __builtin_bit_cast(half8, r);
}

// stage hT from f32 source (layer 0): cvt + swizzled LDS writes (R9-exact)
__device__ inline void stage_f32(_Float16* hT, const float* src0, int rb, int tid) {
  int r = tid >> 2, sg = tid & 3;
  const float* src = src0 + (size_t)(rb * 128 + r) * 256 + sg * 64;
  char* dst = (char*)hT + r * 512;
  int xo = (r & 7) << 4;
#pragma unroll
  for (int oc = 0; oc < 8; ++oc) {
    float4 f0 = *(const float4*)(src + oc * 8);
    float4 f1 = *(const float4*)(src + oc * 8 + 4);
    half8 hv;
    hv[0] = (_Float16)f0.x; hv[1] = (_Float16)f0.y;
    hv[2] = (_Float16)f0.z; hv[3] = (_Float16)f0.w;
    hv[4] = (_Float16)f1.x; hv[5] = (_Float16)f1.y;
    hv[6] = (_Float16)f1.z; hv[7] = (_Float16)f1.w;
    *(half8*)(dst + ((sg * 128 + oc * 16) ^ xo)) = hv;
  }
}

// stage hT from pre-swizzled f16 source: linear 64-KB global_load_lds copy
__device__ inline void stage_f16(_Float16* hT, const char* h, int rb, int tid) {
#pragma unroll
  for (int it = 0; it < 8; ++it)
    gload_lds16(h + (size_t)rb * 65536 + it * 8192 + tid * 16,
                (char*)hT + it * 8192 + tid * 16);
}

// ---------------------------------------------------------------------------
// Main quadratic GEMM (layers 0/1), R9-exact math; NEW: per-wave block
// STAGGER. Same-SIMD wave pairs are (wid, wid+4), so wave group wid>>2
// starts the 18-block sequence at offset 9 and wraps. Anti-phases the two
// co-resident waves per SIMD: one wave's pk_mul burst overlaps the other's
// MFMA-pipe occupancy instead of contending in lockstep. Accumulation is
// per-wave and order-independent (fp32 rounding shuffle only).
template <int F16IN>
__global__ __launch_bounds__(512, 1) void qgemm_main(
    const void* __restrict__ hIn, const _Float16* __restrict__ Wt,
    float* __restrict__ part, const uint32_t* __restrict__ gtab) {
  __shared__ _Float16 hT[128 * 256];     // 64 KB, 512 B/row, XOR-swizzled cols

  const int tid = threadIdx.x;
  const int l = tid & 63;
  const int wid = tid >> 6;
  const int kch = blockIdx.x & 7;   // same-chunk WGs share an XCD (L2-resident Wt)
  const int rb = blockIdx.x >> 3;
  const int tbase = kch * TPC;

  const char* gb = (const char*)Wt + (size_t)tbase * 16384;
  const char* gq = gb + 16384;           // quad tiles start
  const uint32_t lo = (uint32_t)(wid * 2048 + l * 16);
  int blk = (wid >> 2) * 9;              // stagger: SIMD-pair anti-phase

  // issue linear-tile B + starting block's groups up front
  half8 blin0 = *(const half8*)(gb + lo);
  half8 blin1 = *(const half8*)(gb + (lo + 1024));
  const char* gqb0 = gq + (size_t)blk * 131072;
  half8 gA[4][2], gB[4][2];
#pragma unroll
  for (int sp = 0; sp < 4; ++sp) {
    gA[sp][0] = *(const half8*)(gqb0 + (lo + sp * 16384u));
    gA[sp][1] = *(const half8*)(gqb0 + (lo + sp * 16384u + 1024u));
  }
#pragma unroll
  for (int sp = 0; sp < 4; ++sp) {
    gB[sp][0] = *(const half8*)(gqb0 + (lo + (4 + sp) * 16384u));
    gB[sp][1] = *(const half8*)(gqb0 + (lo + (4 + sp) * 16384u + 1024u));
  }
  uint32_t e = gtab[tbase + 1 + blk * 8];

  if (F16IN) stage_f16(hT, (const char*)hIn, rb, tid);
  else       stage_f32(hT, (const float*)hIn, rb, tid);
  __syncthreads();

  floatx4 acc[8][2];
#pragma unroll
  for (int mt = 0; mt < 8; ++mt)
#pragma unroll
    for (int nt = 0; nt < 2; ++nt)
#pragma unroll
      for (int rg = 0; rg < 4; ++rg) acc[mt][nt][rg] = 0.f;

  int rowb[8];
#pragma unroll
  for (int mt = 0; mt < 8; ++mt) rowb[mt] = (mt * 16 + (l & 15)) * 512;
  const int xorb = (l & 7) << 4;
  const int koffA = (l >> 4) * 16;
  const char* hTb = (const char*)hT;

  half8 a[8];
  int prevjb;

  // ---- tile 0: linear (scale = 1) ----
  {
    uint32_t e0 = gtab[tbase];
    int jb = (int)(e0 & 0xFFFFu);
#pragma unroll
    for (int mt = 0; mt < 8; ++mt)
      a[mt] = *(const half8*)(hTb + rowb[mt] + ((jb * 2 + koffA) ^ xorb));
#pragma unroll
    for (int mt = 0; mt < 8; ++mt) {
      acc[mt][0] = mfma16(a[mt], blin0, acc[mt][0]);
      acc[mt][1] = mfma16(a[mt], blin1, acc[mt][1]);
    }
    prevjb = jb;
  }

  // ---- 18 blocks of 8 quad tiles, wrapped order per wave ----
  for (int bb = 0; bb < 18; ++bb) {
    int nblk = (blk == 17) ? 0 : blk + 1;
    uint32_t enext = (bb < 17) ? gtab[tbase + 1 + nblk * 8] : 0u;
    int i0b = (int)(e >> 16);        // block-start i0 (multiple of 8)
    int jb = (int)(e & 0xFFFFu);
    uint4v scu[8];
#pragma unroll
    for (int mt = 0; mt < 8; ++mt)
      scu[mt] = *(const uint4v*)(hTb + rowb[mt] + ((i0b * 2) ^ xorb));
    if (jb != prevjb) {
      prevjb = jb;
#pragma unroll
      for (int mt = 0; mt < 8; ++mt)
        a[mt] = *(const half8*)(hTb + rowb[mt] + ((jb * 2 + koffA) ^ xorb));
    }
    const char* gqn = gq + (size_t)nblk * 131072;

    // consume A-group (tiles 0-3)
#pragma unroll
    for (int sp = 0; sp < 4; ++sp) {
#pragma unroll
      for (int mt = 0; mt < 8; ++mt) {
        half8 as_ = (sp & 1) ? splat_mul_hi(a[mt], scu[mt][sp >> 1])
                             : splat_mul_lo(a[mt], scu[mt][sp >> 1]);
        acc[mt][0] = mfma16(as_, gA[sp][0], acc[mt][0]);
        acc[mt][1] = mfma16(as_, gA[sp][1], acc[mt][1]);
      }
    }
    if (bb < 17) {
#pragma unroll
      for (int sp = 0; sp < 4; ++sp) {
        gA[sp][0] = *(const half8*)(gqn + (lo + sp * 16384u));
        gA[sp][1] = *(const half8*)(gqn + (lo + sp * 16384u + 1024u));
      }
    }
    // consume B-group (tiles 4-7)
#pragma unroll
    for (int sp = 0; sp < 4; ++sp) {
#pragma unroll
      for (int mt = 0; mt < 8; ++mt) {
        half8 as_ = (sp & 1) ? splat_mul_hi(a[mt], scu[mt][2 + (sp >> 1)])
                             : splat_mul_lo(a[mt], scu[mt][2 + (sp >> 1)]);
        acc[mt][0] = mfma16(as_, gB[sp][0], acc[mt][0]);
        acc[mt][1] = mfma16(as_, gB[sp][1], acc[mt][1]);
      }
    }
    if (bb < 17) {
#pragma unroll
      for (int sp = 0; sp < 4; ++sp) {
        gB[sp][0] = *(const half8*)(gqn + (lo + (4 + sp) * 16384u));
        gB[sp][1] = *(const half8*)(gqn + (lo + (4 + sp) * 16384u + 1024u));
      }
    }
    blk = nblk;
    e = enext;
  }

  // ---- epilogue: plain stores to this chunk's partial buffer ----
  float* op = part + (size_t)kch * 1048576;
  const int r0 = rb * 128;
  const int c0 = wid * 32;
#pragma unroll
  for (int mt = 0; mt < 8; ++mt) {
    int rbase = r0 + mt * 16 + (l >> 4) * 4;
#pragma unroll
    for (int nt = 0; nt < 2; ++nt) {
      int c = c0 + nt * 16 + (l & 15);
#pragma unroll
      for (int rg = 0; rg < 4; ++rg)
        op[(size_t)(rbase + rg) * 256 + c] = acc[mt][nt][rg];
    }
  }
}

// ---------------------------------------------------------------------------
// Layer 2 (O=10): f16-staged h2, split-K x2 (grid 512). R14-proven loop.
__global__ __launch_bounds__(512, 2) void qgemm_small(
    const void* __restrict__ hIn, const _Float16* __restrict__ Wt,
    float* __restrict__ part2, const uint32_t* __restrict__ gtab) {
  __shared__ _Float16 hT[128 * 256];
  const int tid = threadIdx.x;
  const int l = tid & 63;
  const int wid = tid >> 6;
  const int kch = blockIdx.x & 7;
  const int rest = blockIdx.x >> 3;
  const int wk = rest & 1;
  const int rb = rest >> 1;
  const int tbase = kch * TPC;

  stage_f16(hT, (const char*)hIn, rb, tid);
  __syncthreads();

  floatx4 acc;
#pragma unroll
  for (int rg = 0; rg < 4; ++rg) acc[rg] = 0.f;

  const int rowb = (wid * 16 + (l & 15)) * 512;
  const int xorb = (l & 7) << 4;
  const int koffA = (l >> 4) * 16;
  const char* hTb = (const char*)hT;

  half8 a, sc;
  int prevjb = -1;

  if (wk == 0) {  // linear tile
    uint32_t e0 = gtab[tbase];
    int jb = (int)(e0 & 0xFFFFu);
    a = *(const half8*)(hTb + rowb + ((jb * 2 + koffA) ^ xorb));
    half8 b = *(const half8*)(Wt + (size_t)tbase * 512 + l * 8);
    acc = mfma16(a, b, acc);
    prevjb = jb;
  }

  for (int u8 = wk * 9; u8 < wk * 9 + 9; ++u8) {
    uint32_t e = gtab[tbase + 1 + u8 * 8];
    int i0b = (int)(e >> 16);
    int jb = (int)(e & 0xFFFFu);
    const int ttb = tbase + 1 + u8 * 8;
    half8 bq[8];
#pragma unroll
    for (int s = 0; s < 8; ++s)
      bq[s] = *(const half8*)(Wt + (size_t)(ttb + s) * 512 + l * 8);
    if (jb != prevjb) {
      prevjb = jb;
      a = *(const half8*)(hTb + rowb + ((jb * 2 + koffA) ^ xorb));
    }
    sc = *(const half8*)(hTb + rowb + ((i0b * 2) ^ xorb));
#pragma unroll
    for (int s = 0; s < 8; ++s) {
      _Float16 sv = sc[s];
      half8 sb = {sv, sv, sv, sv, sv, sv, sv, sv};
      acc = mfma16(a * sb, bq[s], acc);
    }
  }

  float* op = part2 + (size_t)(kch * 2 + wk) * 65536;
  const int r0 = rb * 128 + wid * 16 + (l >> 4) * 4;
  const int c = l & 15;
#pragma unroll
  for (int rg = 0; rg < 4; ++rg)
    op[(size_t)(r0 + rg) * 16 + c] = acc[rg];
}

// ---------------------------------------------------------------------------
extern "C" void kernel_launch(void* const* d_in, const int* in_sizes, int n_in,
                              void* d_out, int out_size, void* d_ws, size_t ws_size,
                              hipStream_t stream) {
  const float* x = (const float*)d_in[0];
  const float* W0 = (const float*)d_in[1];
  const float* b0 = (const float*)d_in[2];
  const float* W1 = (const float*)d_in[3];
  const float* b1 = (const float*)d_in[4];
  const float* W2 = (const float*)d_in[5];
  const float* b2 = (const float*)d_in[6];
  float* out = (float*)d_out;

  char* ws = (char*)d_ws;
  char* h1 = ws;                                           // 2 MB f16 swizzled
  char* h2 = ws + (4u << 20);                              // 2 MB f16 swizzled
  _Float16* Wt = (_Float16*)(ws + (8u << 20));             // 19,005,440 B
  uint32_t* tab = (uint32_t*)(ws + (8u << 20) + 19005440u);
  float* part = (float*)(ws + (28u << 20));                // 8 x 4 MB partials
  float* part2 = part;                                     // reuse (4 MB, 16 bufs)

  build_tab<<<(NTILES + 255) / 256, 256, 0, stream>>>(tab);

  // layer 0
  convert_w2<<<NTILES, 256, 0, stream>>>(W0, Wt, tab);
  qgemm_main<0><<<256, 512, 0, stream>>>(x, Wt, part, tab);
  reduce_h16<<<1024, 256, 0, stream>>>(part, b0, h1);
  // layer 1
  convert_w2<<<NTILES, 256, 0, stream>>>(W1, Wt, tab);
  qgemm_main<1><<<256, 512, 0, stream>>>(h1, Wt, part, tab);
  reduce_h16<<<1024, 256, 0, stream>>>(part, b1, h2);
  // layer 2
  convert_w<<<(NTILES * 1 * 64 + 255) / 256, 256, 0, stream>>>(W2, Wt, tab, 1, 10);
  qgemm_small<<<512, 512, 0, stream>>>(h2, Wt, part2, tab);
  reduce_out<<<160, 256, 0, stream>>>(part2, b2, out);
}

// Round 18
// 200.581 us; speedup vs baseline: 1.0366x; 1.0366x over previous
//
#include <hip/hip_runtime.h>
#include <stdint.h>

#define Q_IN 33152
#define NTILES 1160   // 8 chunks x 145 tiles (1 linear + 144 quad)
#define TPC 145

typedef _Float16 half8 __attribute__((ext_vector_type(8)));
typedef _Float16 half4 __attribute__((ext_vector_type(4)));
typedef float floatx4 __attribute__((ext_vector_type(4)));
typedef uint32_t uint4v __attribute__((ext_vector_type(4)));

// ---------------------------------------------------------------------------
// Tile table in EXECUTION order, chunk-major: T = kch*145 + tt.
// tt=0: linear segment (i0=-1, jb=32*kch). tt>=1: quad tile Q = kch*144+tt-1,
// group-major (g, jt) with jb = 32*(g+jt), inner s=0..31, i0 = 32g+s.
__global__ void build_tab(uint32_t* tab) {
  int T = blockIdx.x * 256 + threadIdx.x;
  if (T >= NTILES) return;
  int kch = T / TPC, tt = T % TPC;
  int i0, jb;
  if (tt == 0) { i0 = -1; jb = 32 * kch; }
  else {
    int Q = kch * 144 + (tt - 1);
    int grp = Q >> 5, s = Q & 31;
    int g = 0, base = 0;
    for (; g < 8; ++g) { int cnt = 8 - g; if (grp < base + cnt) break; base += cnt; }
    int jt = grp - base;
    i0 = 32 * g + s;
    jb = 32 * (g + jt);
  }
  tab[T] = (((uint32_t)(uint16_t)(short)i0) << 16) | (uint32_t)(uint16_t)jb;
}

// ---------------------------------------------------------------------------
// Main-layer W convert (Oreal=256, NTT=16), transpose-through-LDS (R16-proven).
__global__ void convert_w2(const float* __restrict__ W, _Float16* __restrict__ Wt,
                           const uint32_t* __restrict__ tab) {
  __shared__ float p[256][33];           // pad 33: bank stride 1, conflict-free
  const int T = blockIdx.x;
  const int tid = threadIdx.x;
  uint32_t e = tab[T];
  int i0 = (short)(e >> 16);
  int jb = (int)(e & 0xFFFFu);
  int q0;
  if (i0 < 0) q0 = jb;
  else {
    int qb = 256 + i0 * 256 - (i0 * (i0 - 1)) / 2 - i0;  // q = qb + j
    q0 = qb + jb;
  }
  {
    int c = tid & 31, r0 = tid >> 5;     // r0 in 0..7
#pragma unroll
    for (int it = 0; it < 32; ++it) {
      int row = it * 8 + r0;
      p[row][c] = W[(size_t)row * Q_IN + q0 + c];
    }
  }
  __syncthreads();
#pragma unroll
  for (int rep = 0; rep < 4; ++rep) {
    int idx = rep * 256 + tid;
    int nt = idx >> 6;
    int l = idx & 63;
    int o = nt * 16 + (l & 15);
    int koff = (l >> 4) * 8;
    half8 v;
#pragma unroll
    for (int t = 0; t < 8; ++t) {
      int j = jb + koff + t;
      float f = p[o][koff + t];
      v[t] = (i0 >= 0 && j < i0) ? (_Float16)0.f : (_Float16)f;
    }
    *(half8*)(Wt + (size_t)(T * 16 + nt) * 512 + l * 8) = v;
  }
}

// ---------------------------------------------------------------------------
// Small W convert (layer 2, NTT=1, Oreal=10): proven original path.
__global__ void convert_w(const float* __restrict__ W, _Float16* __restrict__ Wt,
                          const uint32_t* __restrict__ tab, int NTT, int Oreal) {
  int tid = blockIdx.x * 256 + threadIdx.x;
  if (tid >= NTILES * NTT * 64) return;
  int l = tid & 63;
  int nt = (tid >> 6) % NTT;
  int T = tid / (64 * NTT);
  int o = nt * 16 + (l & 15);
  int koff = (l >> 4) * 8;
  half8 v;
#pragma unroll
  for (int t = 0; t < 8; ++t) v[t] = (_Float16)0.f;
  if (o < Oreal) {
    uint32_t e = tab[T];
    int i0 = (short)(e >> 16);
    int jb = (int)(e & 0xFFFFu);
    const float* row = W + (size_t)o * Q_IN;
    if (i0 < 0) {
#pragma unroll
      for (int t = 0; t < 8; ++t) v[t] = (_Float16)row[jb + koff + t];
    } else {
      int qb = 256 + i0 * 256 - (i0 * (i0 - 1)) / 2 - i0;  // q = qb + j
#pragma unroll
      for (int t = 0; t < 8; ++t) {
        int j = jb + koff + t;
        if (j >= i0) v[t] = (_Float16)row[qb + j];
      }
    }
  }
  *(half8*)(Wt + (size_t)(T * NTT + nt) * 512 + l * 8) = v;
}

// ---------------------------------------------------------------------------
// reduce f16 partials + bias -> h in f16, ALREADY in the hT byte layout:
// byte(row,col) = row*512 + ((col*2) ^ ((row&7)<<4)). 4 cols per thread.
__global__ void reduce_h16(const _Float16* __restrict__ part,
                           const float* __restrict__ bias, char* __restrict__ h) {
  int t = blockIdx.x * 256 + threadIdx.x;     // 262144 threads
  int row = t >> 6, c4 = (t & 63) << 2;
  float4 acc = *(const float4*)(bias + c4);
#pragma unroll
  for (int k = 0; k < 8; ++k) {
    half4 p4 = *(const half4*)(part + (size_t)k * 1048576 + t * 4);
    acc.x += (float)p4[0]; acc.y += (float)p4[1];
    acc.z += (float)p4[2]; acc.w += (float)p4[3];
  }
  _Float16 hv[4] = {(_Float16)acc.x, (_Float16)acc.y, (_Float16)acc.z, (_Float16)acc.w};
  *(uint64_t*)(h + (size_t)row * 512 + ((c4 * 2) ^ ((row & 7) << 4))) =
      *(const uint64_t*)hv;
}

// reduce partials + bias -> out (4096 x 10), part2 stride 16, 16 partials
__global__ void reduce_out(const float* __restrict__ part2, const float* __restrict__ b2,
                           float* __restrict__ out) {
  int t = blockIdx.x * 256 + threadIdx.x;     // 40960
  if (t >= 40960) return;
  int b = t / 10, o = t - b * 10;
  float acc = b2[o];
#pragma unroll
  for (int k = 0; k < 16; ++k) acc += part2[(size_t)k * 65536 + b * 16 + o];
  out[t] = acc;
}

__device__ inline floatx4 mfma16(half8 a, half8 b, floatx4 c) {
  return __builtin_amdgcn_mfma_f32_16x16x32_f16(a, b, c, 0, 0, 0);
}

__device__ inline void gload_lds16(const void* g, void* l) {
  __builtin_amdgcn_global_load_lds(
      (const __attribute__((address_space(1))) uint32_t*)g,
      (__attribute__((address_space(3))) uint32_t*)l, 16, 0, 0);
}

// a * broadcast(lo/hi half of s) via v_pk_mul_f16 op_sel (R9-proven)
__device__ inline half8 splat_mul_lo(half8 a, uint32_t s) {
  uint4v av = __builtin_bit_cast(uint4v, a), r;
#pragma unroll
  for (int k = 0; k < 4; ++k)
    asm("v_pk_mul_f16 %0, %1, %2 op_sel:[0,0] op_sel_hi:[1,0]"
        : "=v"(r[k]) : "v"(av[k]), "v"(s));
  return __builtin_bit_cast(half8, r);
}
__device__ inline half8 splat_mul_hi(half8 a, uint32_t s) {
  uint4v av = __builtin_bit_cast(uint4v, a), r;
#pragma unroll
  for (int k = 0; k < 4; ++k)
    asm("v_pk_mul_f16 %0, %1, %2 op_sel:[0,1] op_sel_hi:[1,1]"
        : "=v"(r[k]) : "v"(av[k]), "v"(s));
  return __builtin_bit_cast(half8, r);
}

// stage hT from f32 source (layer 0): cvt + swizzled LDS writes (R9-exact)
__device__ inline void stage_f32(_Float16* hT, const float* src0, int rb, int tid) {
  int r = tid >> 2, sg = tid & 3;
  const float* src = src0 + (size_t)(rb * 128 + r) * 256 + sg * 64;
  char* dst = (char*)hT + r * 512;
  int xo = (r & 7) << 4;
#pragma unroll
  for (int oc = 0; oc < 8; ++oc) {
    float4 f0 = *(const float4*)(src + oc * 8);
    float4 f1 = *(const float4*)(src + oc * 8 + 4);
    half8 hv;
    hv[0] = (_Float16)f0.x; hv[1] = (_Float16)f0.y;
    hv[2] = (_Float16)f0.z; hv[3] = (_Float16)f0.w;
    hv[4] = (_Float16)f1.x; hv[5] = (_Float16)f1.y;
    hv[6] = (_Float16)f1.z; hv[7] = (_Float16)f1.w;
    *(half8*)(dst + ((sg * 128 + oc * 16) ^ xo)) = hv;
  }
}

// stage hT from pre-swizzled f16 source: linear 64-KB global_load_lds copy
__device__ inline void stage_f16(_Float16* hT, const char* h, int rb, int tid) {
#pragma unroll
  for (int it = 0; it < 8; ++it)
    gload_lds16(h + (size_t)rb * 65536 + it * 8192 + tid * 16,
                (char*)hT + it * 8192 + tid * 16);
}

// ---------------------------------------------------------------------------
// Main quadratic GEMM (layers 0/1), R16-exact K-loop: BM=128, N=256, 8 waves
// (1M x 8N), per-wave 128x32 (MT=8, NTW=2). A-octets + scales in registers,
// B global->reg 2-group (8-tile) pipeline, no barriers. f16 partial stores.
template <int F16IN>
__global__ __launch_bounds__(512, 1) void qgemm_main(
    const void* __restrict__ hIn, const _Float16* __restrict__ Wt,
    _Float16* __restrict__ part, const uint32_t* __restrict__ gtab) {
  __shared__ _Float16 hT[128 * 256];     // 64 KB, 512 B/row, XOR-swizzled cols

  const int tid = threadIdx.x;
  const int l = tid & 63;
  const int wid = tid >> 6;
  const int kch = blockIdx.x & 7;   // same-chunk WGs share an XCD (L2-resident Wt)
  const int rb = blockIdx.x >> 3;
  const int tbase = kch * TPC;

  const char* gb = (const char*)Wt + (size_t)tbase * 16384;
  const uint32_t lo = (uint32_t)(wid * 2048 + l * 16);

  // issue linear-tile B + block-0 groups up front (latency hides under staging)
  half8 blin0 = *(const half8*)(gb + lo);
  half8 blin1 = *(const half8*)(gb + (lo + 1024));
  const char* gq = gb + 16384;           // quad tiles start
  half8 gA[4][2], gB[4][2];
#pragma unroll
  for (int sp = 0; sp < 4; ++sp) {
    gA[sp][0] = *(const half8*)(gq + (lo + sp * 16384u));
    gA[sp][1] = *(const half8*)(gq + (lo + sp * 16384u + 1024u));
  }
#pragma unroll
  for (int sp = 0; sp < 4; ++sp) {
    gB[sp][0] = *(const half8*)(gq + (lo + (4 + sp) * 16384u));
    gB[sp][1] = *(const half8*)(gq + (lo + (4 + sp) * 16384u + 1024u));
  }

  if (F16IN) stage_f16(hT, (const char*)hIn, rb, tid);
  else       stage_f32(hT, (const float*)hIn, rb, tid);
  __syncthreads();

  floatx4 acc[8][2];
#pragma unroll
  for (int mt = 0; mt < 8; ++mt)
#pragma unroll
    for (int nt = 0; nt < 2; ++nt)
#pragma unroll
      for (int rg = 0; rg < 4; ++rg) acc[mt][nt][rg] = 0.f;

  int rowb[8];
#pragma unroll
  for (int mt = 0; mt < 8; ++mt) rowb[mt] = (mt * 16 + (l & 15)) * 512;
  const int xorb = (l & 7) << 4;
  const int koffA = (l >> 4) * 16;
  const char* hTb = (const char*)hT;

  half8 a[8];
  int prevjb;

  // ---- tile 0: linear (scale = 1) ----
  {
    uint32_t e0 = gtab[tbase];
    int jb = (int)(e0 & 0xFFFFu);
#pragma unroll
    for (int mt = 0; mt < 8; ++mt)
      a[mt] = *(const half8*)(hTb + rowb[mt] + ((jb * 2 + koffA) ^ xorb));
#pragma unroll
    for (int mt = 0; mt < 8; ++mt) {
      acc[mt][0] = mfma16(a[mt], blin0, acc[mt][0]);
      acc[mt][1] = mfma16(a[mt], blin1, acc[mt][1]);
    }
    prevjb = jb;
  }

  // ---- 18 blocks of 8 quad tiles; 2-group register pipeline ----
  uint32_t e = gtab[tbase + 1];
  for (int b = 0; b < 18; ++b) {
    uint32_t enext = (b < 17) ? gtab[tbase + 1 + (b + 1) * 8] : 0u;
    int i0b = (int)(e >> 16);        // block-start i0 (multiple of 8)
    int jb = (int)(e & 0xFFFFu);
    uint4v scu[8];
#pragma unroll
    for (int mt = 0; mt < 8; ++mt)
      scu[mt] = *(const uint4v*)(hTb + rowb[mt] + ((i0b * 2) ^ xorb));
    if (jb != prevjb) {
      prevjb = jb;
#pragma unroll
      for (int mt = 0; mt < 8; ++mt)
        a[mt] = *(const half8*)(hTb + rowb[mt] + ((jb * 2 + koffA) ^ xorb));
    }
    const char* gqn = gq + 131072;

    // consume A-group (tiles 0-3)
#pragma unroll
    for (int sp = 0; sp < 4; ++sp) {
#pragma unroll
      for (int mt = 0; mt < 8; ++mt) {
        half8 as_ = (sp & 1) ? splat_mul_hi(a[mt], scu[mt][sp >> 1])
                             : splat_mul_lo(a[mt], scu[mt][sp >> 1]);
        acc[mt][0] = mfma16(as_, gA[sp][0], acc[mt][0]);
        acc[mt][1] = mfma16(as_, gA[sp][1], acc[mt][1]);
      }
    }
    if (b < 17) {
#pragma unroll
      for (int sp = 0; sp < 4; ++sp) {
        gA[sp][0] = *(const half8*)(gqn + (lo + sp * 16384u));
        gA[sp][1] = *(const half8*)(gqn + (lo + sp * 16384u + 1024u));
      }
    }
    // consume B-group (tiles 4-7)
#pragma unroll
    for (int sp = 0; sp < 4; ++sp) {
#pragma unroll
      for (int mt = 0; mt < 8; ++mt) {
        half8 as_ = (sp & 1) ? splat_mul_hi(a[mt], scu[mt][2 + (sp >> 1)])
                             : splat_mul_lo(a[mt], scu[mt][2 + (sp >> 1)]);
        acc[mt][0] = mfma16(as_, gB[sp][0], acc[mt][0]);
        acc[mt][1] = mfma16(as_, gB[sp][1], acc[mt][1]);
      }
    }
    if (b < 17) {
#pragma unroll
      for (int sp = 0; sp < 4; ++sp) {
        gB[sp][0] = *(const half8*)(gqn + (lo + (4 + sp) * 16384u));
        gB[sp][1] = *(const half8*)(gqn + (lo + (4 + sp) * 16384u + 1024u));
      }
    }
    gq = gqn;
    e = enext;
  }

  // ---- epilogue: f16 stores to this chunk's partial buffer ----
  _Float16* op = part + (size_t)kch * 1048576;
  const int r0 = rb * 128;
  const int c0 = wid * 32;
#pragma unroll
  for (int mt = 0; mt < 8; ++mt) {
    int rbase = r0 + mt * 16 + (l >> 4) * 4;
#pragma unroll
    for (int nt = 0; nt < 2; ++nt) {
      int c = c0 + nt * 16 + (l & 15);
#pragma unroll
      for (int rg = 0; rg < 4; ++rg)
        op[(size_t)(rbase + rg) * 256 + c] = (_Float16)acc[mt][nt][rg];
    }
  }
}

// ---------------------------------------------------------------------------
// Layer 2 (O=10): NO LDS staging — h2 (2 MB, pre-swizzled f16) is L2-resident;
// A-octets/scales read directly from global. Split-K x2, grid 512, 16 waves/CU.
__global__ __launch_bounds__(512, 2) void qgemm_small(
    const char* __restrict__ h2, const _Float16* __restrict__ Wt,
    float* __restrict__ part2, const uint32_t* __restrict__ gtab) {
  const int tid = threadIdx.x;
  const int l = tid & 63;
  const int wid = tid >> 6;
  const int kch = blockIdx.x & 7;
  const int rest = blockIdx.x >> 3;
  const int wk = rest & 1;
  const int rb = rest >> 1;
  const int tbase = kch * TPC;

  floatx4 acc;
#pragma unroll
  for (int rg = 0; rg < 4; ++rg) acc[rg] = 0.f;

  const char* hb = h2 + (size_t)rb * 65536;   // this row-block, hT byte layout
  const int rowb = (wid * 16 + (l & 15)) * 512;
  const int xorb = (l & 7) << 4;
  const int koffA = (l >> 4) * 16;

  half8 a, sc;
  int prevjb = -1;

  if (wk == 0) {  // linear tile
    uint32_t e0 = gtab[tbase];
    int jb = (int)(e0 & 0xFFFFu);
    a = *(const half8*)(hb + rowb + ((jb * 2 + koffA) ^ xorb));
    half8 b = *(const half8*)(Wt + (size_t)tbase * 512 + l * 8);
    acc = mfma16(a, b, acc);
    prevjb = jb;
  }

  for (int u8 = wk * 9; u8 < wk * 9 + 9; ++u8) {
    uint32_t e = gtab[tbase + 1 + u8 * 8];
    int i0b = (int)(e >> 16);
    int jb = (int)(e & 0xFFFFu);
    const int ttb = tbase + 1 + u8 * 8;
    half8 bq[8];
#pragma unroll
    for (int s = 0; s < 8; ++s)
      bq[s] = *(const half8*)(Wt + (size_t)(ttb + s) * 512 + l * 8);
    if (jb != prevjb) {
      prevjb = jb;
      a = *(const half8*)(hb + rowb + ((jb * 2 + koffA) ^ xorb));
    }
    sc = *(const half8*)(hb + rowb + ((i0b * 2) ^ xorb));
#pragma unroll
    for (int s = 0; s < 8; ++s) {
      _Float16 sv = sc[s];
      half8 sb = {sv, sv, sv, sv, sv, sv, sv, sv};
      acc = mfma16(a * sb, bq[s], acc);
    }
  }

  float* op = part2 + (size_t)(kch * 2 + wk) * 65536;
  const int r0 = rb * 128 + wid * 16 + (l >> 4) * 4;
  const int c = l & 15;
#pragma unroll
  for (int rg = 0; rg < 4; ++rg)
    op[(size_t)(r0 + rg) * 16 + c] = acc[rg];
}

// ---------------------------------------------------------------------------
extern "C" void kernel_launch(void* const* d_in, const int* in_sizes, int n_in,
                              void* d_out, int out_size, void* d_ws, size_t ws_size,
                              hipStream_t stream) {
  const float* x = (const float*)d_in[0];
  const float* W0 = (const float*)d_in[1];
  const float* b0 = (const float*)d_in[2];
  const float* W1 = (const float*)d_in[3];
  const float* b1 = (const float*)d_in[4];
  const float* W2 = (const float*)d_in[5];
  const float* b2 = (const float*)d_in[6];
  float* out = (float*)d_out;

  char* ws = (char*)d_ws;
  char* h1 = ws;                                           // 2 MB f16 swizzled
  char* h2 = ws + (4u << 20);                              // 2 MB f16 swizzled
  _Float16* Wt = (_Float16*)(ws + (8u << 20));             // 19,005,440 B
  uint32_t* tab = (uint32_t*)(ws + (8u << 20) + 19005440u);
  _Float16* part = (_Float16*)(ws + (28u << 20));          // 8 x 2 MB f16 partials
  float* part2 = (float*)(ws + (44u << 20));               // 16 x 256 KB f32

  build_tab<<<(NTILES + 255) / 256, 256, 0, stream>>>(tab);

  // layer 0
  convert_w2<<<NTILES, 256, 0, stream>>>(W0, Wt, tab);
  qgemm_main<0><<<256, 512, 0, stream>>>(x, Wt, part, tab);
  reduce_h16<<<1024, 256, 0, stream>>>(part, b0, h1);
  // layer 1
  convert_w2<<<NTILES, 256, 0, stream>>>(W1, Wt, tab);
  qgemm_main<1><<<256, 512, 0, stream>>>(h1, Wt, part, tab);
  reduce_h16<<<1024, 256, 0, stream>>>(part, b1, h2);
  // layer 2
  convert_w<<<(NTILES * 1 * 64 + 255) / 256, 256, 0, stream>>>(W2, Wt, tab, 1, 10);
  qgemm_small<<<512, 512, 0, stream>>>(h2, Wt, part2, tab);
  reduce_out<<<160, 256, 0, stream>>>(part2, b2, out);
}